// Round 2
// baseline (970.226 us; speedup 1.0000x reference)
//
#include <hip/hip_runtime.h>

#define NN 50000      // nodes
#define NE 800000     // edges
#define DF 64         // features
#define MM 11         // (a,b) tuples
#define OUT_K 4       // DEPTH+1 output planes

// ---------------- CSR build (runs once, independent of feature passes) ----------------

__global__ void k_deg(const int* __restrict__ row, int* __restrict__ deg) {
    int e = blockIdx.x * blockDim.x + threadIdx.x;
    if (e < NE) atomicAdd(&deg[row[e]], 1);
}

// Disjoint slab per row: wave-local prefix scan + one atomicAdd per wave.
// Slab ordering across waves is irrelevant (only disjointness matters).
__global__ void k_alloc(const int* __restrict__ deg, int* __restrict__ counter,
                        int* __restrict__ rowstart) {
    int i = blockIdx.x * blockDim.x + threadIdx.x;
    int lane = threadIdx.x & 63;
    int d = (i < NN) ? deg[i] : 0;
    int v = d;
    #pragma unroll
    for (int off = 1; off < 64; off <<= 1) {
        int t = __shfl_up(v, off, 64);
        if (lane >= off) v += t;
    }
    int total = __shfl(v, 63, 64);
    int base = 0;
    if (lane == 63) base = atomicAdd(counter, total);
    base = __shfl(base, 63, 64);
    if (i < NN) rowstart[i] = base + v - d;
}

__global__ void k_dinv(const int* __restrict__ deg, float* __restrict__ dinv) {
    int i = blockIdx.x * blockDim.x + threadIdx.x;
    if (i < NN) {
        int d = deg[i];
        dinv[i] = 1.0f / sqrtf((float)(d == 0 ? 1 : d));
    }
}

__global__ void k_fill(const int* __restrict__ row, const int* __restrict__ col,
                       const float* __restrict__ ea, const float* __restrict__ dinv,
                       const int* __restrict__ rowstart, int* __restrict__ fill,
                       int* __restrict__ ccol, float* __restrict__ cval) {
    int e = blockIdx.x * blockDim.x + threadIdx.x;
    if (e < NE) {
        int r = row[e], c = col[e];
        int pos = rowstart[r] + atomicAdd(&fill[r], 1);
        ccol[pos] = c;
        cval[pos] = dinv[r] * ea[e] * dinv[c];
    }
}

// ---------------- Stage kernels, templated on feature-chunk width DC ----------------
// One row per DC-lane sub-wave; lane = feature within the chunk. d0 = chunk offset.

template <int DC>
__global__ __launch_bounds__(256) void k_stage1(
    const int* __restrict__ rowstart, const int* __restrict__ deg,
    const int* __restrict__ ccol, const float* __restrict__ cval,
    const float* __restrict__ x, const float* __restrict__ alphas,
    const float* __restrict__ w, const float* __restrict__ a_arr,
    const float* __restrict__ b_arr,
    float* __restrict__ xs1, float* __restrict__ out, int d0) {
    int r = (blockIdx.x * blockDim.x + threadIdx.x) / DC;
    int lane = threadIdx.x & (DC - 1);
    if (r >= NN) return;
    int s = rowstart[r], e = s + deg[r];
    float acc = 0.f;
    for (int i = s; i < e; ++i) {
        int c = ccol[i];
        float v = cval[i];
        acc += v * x[c * DF + d0 + lane];
    }
    float xr = x[r * DF + d0 + lane];
    float out1 = 0.f, wsum = 0.f;
    #pragma unroll
    for (int m = 0; m < MM; ++m) {
        float a = a_arr[m], b = b_arr[m];
        float al0 = alphas[m];
        float wm = w[m];
        float c1 = 0.5f * (a - b);
        float c2 = 0.5f * (a + b + 2.f);
        float v = al0 * (c1 * xr + c2 * acc);
        xs1[(r * MM + m) * DC + lane] = v;
        out1 += wm * v;
        wsum += wm;
    }
    out[(r * OUT_K + 0) * DF + d0 + lane] = wsum * xr;
    out[(r * OUT_K + 1) * DF + d0 + lane] = out1;
}

template <int DC>
__global__ __launch_bounds__(256) void k_stage2(
    const int* __restrict__ rowstart, const int* __restrict__ deg,
    const int* __restrict__ ccol, const float* __restrict__ cval,
    const float* __restrict__ xs1, const float* __restrict__ x,
    const float* __restrict__ alphas, const float* __restrict__ w,
    const float* __restrict__ a_arr, const float* __restrict__ b_arr,
    float* __restrict__ xs2, float* __restrict__ out, int d0) {
    int r = (blockIdx.x * blockDim.x + threadIdx.x) / DC;
    int lane = threadIdx.x & (DC - 1);
    if (r >= NN) return;
    int s = rowstart[r], e = s + deg[r];
    float accs[MM];
    #pragma unroll
    for (int m = 0; m < MM; ++m) accs[m] = 0.f;
    for (int i = s; i < e; ++i) {
        int c = ccol[i];
        float v = cval[i];
        const float* p = xs1 + c * (MM * DC) + lane;
        #pragma unroll
        for (int m = 0; m < MM; ++m) accs[m] += v * p[m * DC];
    }
    float xr = x[r * DF + d0 + lane];
    const float* pr = xs1 + r * (MM * DC) + lane;
    float out2 = 0.f;
    #pragma unroll
    for (int m = 0; m < MM; ++m) {
        float a = a_arr[m], b = b_arr[m];
        float alL = alphas[1 * MM + m], alLm1 = alphas[0 * MM + m];
        float wm = w[m];
        const float Lf = 2.f;
        float ab = a + b;
        float t2L = 2.f * Lf + ab;
        float coef_l = 2.f * Lf * (Lf + ab) * (t2L - 2.f);
        float inv = 1.f / coef_l;
        float tmp1 = alL * ((t2L - 1.f) * t2L * (t2L - 2.f)) * inv;
        float tmp2 = alL * ((t2L - 1.f) * (a * a - b * b)) * inv;
        float tmp3 = alL * alLm1 * (2.f * (Lf - 1.f + a) * (Lf - 1.f + b) * t2L) * inv;
        float nx = tmp1 * accs[m] - tmp2 * pr[m * DC] - tmp3 * xr;
        xs2[(r * MM + m) * DC + lane] = nx;
        out2 += wm * nx;
    }
    out[(r * OUT_K + 2) * DF + d0 + lane] = out2;
}

template <int DC>
__global__ __launch_bounds__(256) void k_stage3(
    const int* __restrict__ rowstart, const int* __restrict__ deg,
    const int* __restrict__ ccol, const float* __restrict__ cval,
    const float* __restrict__ xs2, const float* __restrict__ xs1,
    const float* __restrict__ alphas, const float* __restrict__ w,
    const float* __restrict__ a_arr, const float* __restrict__ b_arr,
    float* __restrict__ out, int d0) {
    int r = (blockIdx.x * blockDim.x + threadIdx.x) / DC;
    int lane = threadIdx.x & (DC - 1);
    if (r >= NN) return;
    int s = rowstart[r], e = s + deg[r];
    float accs[MM];
    #pragma unroll
    for (int m = 0; m < MM; ++m) accs[m] = 0.f;
    for (int i = s; i < e; ++i) {
        int c = ccol[i];
        float v = cval[i];
        const float* p = xs2 + c * (MM * DC) + lane;
        #pragma unroll
        for (int m = 0; m < MM; ++m) accs[m] += v * p[m * DC];
    }
    const float* pr  = xs2 + r * (MM * DC) + lane;
    const float* pr2 = xs1 + r * (MM * DC) + lane;
    float out3 = 0.f;
    #pragma unroll
    for (int m = 0; m < MM; ++m) {
        float a = a_arr[m], b = b_arr[m];
        float alL = alphas[2 * MM + m], alLm1 = alphas[1 * MM + m];
        float wm = w[m];
        const float Lf = 3.f;
        float ab = a + b;
        float t2L = 2.f * Lf + ab;
        float coef_l = 2.f * Lf * (Lf + ab) * (t2L - 2.f);
        float inv = 1.f / coef_l;
        float tmp1 = alL * ((t2L - 1.f) * t2L * (t2L - 2.f)) * inv;
        float tmp2 = alL * ((t2L - 1.f) * (a * a - b * b)) * inv;
        float tmp3 = alL * alLm1 * (2.f * (Lf - 1.f + a) * (Lf - 1.f + b) * t2L) * inv;
        float nx = tmp1 * accs[m] - tmp2 * pr[m * DC] - tmp3 * pr2[m * DC];
        out3 += wm * nx;
    }
    out[(r * OUT_K + 3) * DF + d0 + lane] = out3;
}

// ---------------- launch ----------------

template <int DC>
static void run_passes(const int* rowstart, const int* deg, const int* ccol,
                       const float* cval, const float* x, const float* alphas,
                       const float* w, const float* a_arr, const float* b_arr,
                       float* xs1, float* xs2, float* out, hipStream_t stream) {
    const int rows_per_block = 256 / DC;
    const int blocks = (NN + rows_per_block - 1) / rows_per_block;
    for (int d0 = 0; d0 < DF; d0 += DC) {
        k_stage1<DC><<<blocks, 256, 0, stream>>>(rowstart, deg, ccol, cval, x,
                                                 alphas, w, a_arr, b_arr, xs1, out, d0);
        k_stage2<DC><<<blocks, 256, 0, stream>>>(rowstart, deg, ccol, cval, xs1, x,
                                                 alphas, w, a_arr, b_arr, xs2, out, d0);
        k_stage3<DC><<<blocks, 256, 0, stream>>>(rowstart, deg, ccol, cval, xs2, xs1,
                                                 alphas, w, a_arr, b_arr, out, d0);
    }
}

extern "C" void kernel_launch(void* const* d_in, const int* in_sizes, int n_in,
                              void* d_out, int out_size, void* d_ws, size_t ws_size,
                              hipStream_t stream) {
    const float* x      = (const float*)d_in[0];
    const int*   ei     = (const int*)d_in[1];
    const float* ea     = (const float*)d_in[2];
    const float* alphas = (const float*)d_in[3];
    const float* w      = (const float*)d_in[4];
    const float* a_arr  = (const float*)d_in[5];
    const float* b_arr  = (const float*)d_in[6];
    float* out = (float*)d_out;
    const int* row = ei;
    const int* col = ei + NE;

    char* ws = (char*)d_ws;
    size_t off = 0;
    auto alloc = [&](size_t bytes) {
        void* p = ws + off;
        off = (off + bytes + 255) & ~(size_t)255;
        return p;
    };
    // deg, fill, counter contiguous so one memset zeroes all three
    int* deg      = (int*)alloc((size_t)(2 * NN + 1) * sizeof(int));
    int* fill     = deg + NN;
    int* counter  = deg + 2 * NN;
    int* rowstart = (int*)alloc((size_t)NN * sizeof(int));
    float* dinv   = (float*)alloc((size_t)NN * sizeof(float));
    int* ccol     = (int*)alloc((size_t)NE * sizeof(int));
    float* cval   = (float*)alloc((size_t)NE * sizeof(float));
    size_t fixed_end = off;

    // Pick the largest feature-chunk DC whose two history tensors fit in ws.
    int DC = 64;
    while (DC > 8) {
        size_t need = fixed_end + 2 * (((size_t)NN * MM * DC * sizeof(float) + 255) & ~(size_t)255);
        if (need <= ws_size) break;
        DC >>= 1;
    }
    float* xs1 = (float*)alloc((size_t)NN * MM * DC * sizeof(float));
    float* xs2 = (float*)alloc((size_t)NN * MM * DC * sizeof(float));

    hipMemsetAsync(deg, 0, (size_t)(2 * NN + 1) * sizeof(int), stream);

    k_deg<<<(NE + 255) / 256, 256, 0, stream>>>(row, deg);
    k_alloc<<<(NN + 255) / 256, 256, 0, stream>>>(deg, counter, rowstart);
    k_dinv<<<(NN + 255) / 256, 256, 0, stream>>>(deg, dinv);
    k_fill<<<(NE + 255) / 256, 256, 0, stream>>>(row, col, ea, dinv, rowstart, fill,
                                                 ccol, cval);

    switch (DC) {
        case 64: run_passes<64>(rowstart, deg, ccol, cval, x, alphas, w, a_arr, b_arr,
                                xs1, xs2, out, stream); break;
        case 32: run_passes<32>(rowstart, deg, ccol, cval, x, alphas, w, a_arr, b_arr,
                                xs1, xs2, out, stream); break;
        case 16: run_passes<16>(rowstart, deg, ccol, cval, x, alphas, w, a_arr, b_arr,
                                xs1, xs2, out, stream); break;
        default: run_passes<8>(rowstart, deg, ccol, cval, x, alphas, w, a_arr, b_arr,
                               xs1, xs2, out, stream); break;
    }
}

// Round 3
// 688.074 us; speedup vs baseline: 1.4101x; 1.4101x over previous
//
#include <hip/hip_runtime.h>

#define NN 50000      // nodes
#define NE 800000     // edges
#define DF 64         // features
#define MM 11         // (a,b) tuples
#define OUT_K 4       // DEPTH+1 output planes

// bf16 <-> f32 helpers (round-to-nearest-even)
__device__ __forceinline__ float bf2f(unsigned short u) {
    union { unsigned int i; float f; } v; v.i = ((unsigned int)u) << 16; return v.f;
}
__device__ __forceinline__ unsigned short f2bf(float f) {
    union { float f; unsigned int i; } v; v.f = f;
    unsigned int u = v.i + 0x7FFFu + ((v.i >> 16) & 1u);
    return (unsigned short)(u >> 16);
}

// ---------------- CSR build (runs once) ----------------

__global__ void k_deg(const int* __restrict__ row, int* __restrict__ deg) {
    int e = blockIdx.x * blockDim.x + threadIdx.x;
    if (e < NE) atomicAdd(&deg[row[e]], 1);
}

// Disjoint slab per row: wave-local prefix scan + one atomicAdd per wave.
__global__ void k_alloc(const int* __restrict__ deg, int* __restrict__ counter,
                        int* __restrict__ rowstart) {
    int i = blockIdx.x * blockDim.x + threadIdx.x;
    int lane = threadIdx.x & 63;
    int d = (i < NN) ? deg[i] : 0;
    int v = d;
    #pragma unroll
    for (int off = 1; off < 64; off <<= 1) {
        int t = __shfl_up(v, off, 64);
        if (lane >= off) v += t;
    }
    int total = __shfl(v, 63, 64);
    int base = 0;
    if (lane == 63) base = atomicAdd(counter, total);
    base = __shfl(base, 63, 64);
    if (i < NN) rowstart[i] = base + v - d;
}

__global__ void k_dinv(const int* __restrict__ deg, float* __restrict__ dinv) {
    int i = blockIdx.x * blockDim.x + threadIdx.x;
    if (i < NN) {
        int d = deg[i];
        dinv[i] = 1.0f / sqrtf((float)(d == 0 ? 1 : d));
    }
}

__global__ void k_fill(const int* __restrict__ row, const int* __restrict__ col,
                       const float* __restrict__ ea, const float* __restrict__ dinv,
                       const int* __restrict__ rowstart, int* __restrict__ fill,
                       int* __restrict__ ccol, float* __restrict__ cval) {
    int e = blockIdx.x * blockDim.x + threadIdx.x;
    if (e < NE) {
        int r = row[e], c = col[e];
        int pos = rowstart[r] + atomicAdd(&fill[r], 1);
        ccol[pos] = c;
        cval[pos] = dinv[r] * ea[e] * dinv[c];
    }
}

// ---------------- Stage kernels (bf16 history), chunk width DC ----------------
// One row per DC-lane sub-wave; lane = feature within chunk; d0 = chunk offset.

template <int DC>
__global__ __launch_bounds__(256) void k_stage1(
    const int* __restrict__ rowstart, const int* __restrict__ deg,
    const int* __restrict__ ccol, const float* __restrict__ cval,
    const float* __restrict__ x, const float* __restrict__ alphas,
    const float* __restrict__ w, const float* __restrict__ a_arr,
    const float* __restrict__ b_arr,
    unsigned short* __restrict__ xs1, float* __restrict__ out, int d0) {
    int r = (blockIdx.x * blockDim.x + threadIdx.x) / DC;
    int lane = threadIdx.x & (DC - 1);
    if (r >= NN) return;
    int s = rowstart[r], e = s + deg[r];
    float acc = 0.f;
    for (int i = s; i < e; ++i) {
        int c = __builtin_nontemporal_load(&ccol[i]);
        float v = __builtin_nontemporal_load(&cval[i]);
        acc += v * x[c * DF + d0 + lane];
    }
    float xr = x[r * DF + d0 + lane];
    float out1 = 0.f, wsum = 0.f;
    #pragma unroll
    for (int m = 0; m < MM; ++m) {
        float a = a_arr[m], b = b_arr[m];
        float al0 = alphas[m];
        float wm = w[m];
        float c1 = 0.5f * (a - b);
        float c2 = 0.5f * (a + b + 2.f);
        float v = al0 * (c1 * xr + c2 * acc);
        xs1[(r * MM + m) * DC + lane] = f2bf(v);
        out1 += wm * v;
        wsum += wm;
    }
    out[(r * OUT_K + 0) * DF + d0 + lane] = wsum * xr;
    out[(r * OUT_K + 1) * DF + d0 + lane] = out1;
}

template <int DC>
__global__ __launch_bounds__(256) void k_stage2(
    const int* __restrict__ rowstart, const int* __restrict__ deg,
    const int* __restrict__ ccol, const float* __restrict__ cval,
    const unsigned short* __restrict__ xs1, const float* __restrict__ x,
    const float* __restrict__ alphas, const float* __restrict__ w,
    const float* __restrict__ a_arr, const float* __restrict__ b_arr,
    unsigned short* __restrict__ xs2, float* __restrict__ out, int d0) {
    int r = (blockIdx.x * blockDim.x + threadIdx.x) / DC;
    int lane = threadIdx.x & (DC - 1);
    if (r >= NN) return;
    int s = rowstart[r], e = s + deg[r];
    float accs[MM];
    #pragma unroll
    for (int m = 0; m < MM; ++m) accs[m] = 0.f;
    for (int i = s; i < e; ++i) {
        int c = __builtin_nontemporal_load(&ccol[i]);
        float v = __builtin_nontemporal_load(&cval[i]);
        const unsigned short* p = xs1 + c * (MM * DC) + lane;
        #pragma unroll
        for (int m = 0; m < MM; ++m) accs[m] += v * bf2f(p[m * DC]);
    }
    float xr = x[r * DF + d0 + lane];
    const unsigned short* pr = xs1 + r * (MM * DC) + lane;
    float out2 = 0.f;
    #pragma unroll
    for (int m = 0; m < MM; ++m) {
        float a = a_arr[m], b = b_arr[m];
        float alL = alphas[1 * MM + m], alLm1 = alphas[0 * MM + m];
        float wm = w[m];
        const float Lf = 2.f;
        float ab = a + b;
        float t2L = 2.f * Lf + ab;
        float coef_l = 2.f * Lf * (Lf + ab) * (t2L - 2.f);
        float inv = 1.f / coef_l;
        float tmp1 = alL * ((t2L - 1.f) * t2L * (t2L - 2.f)) * inv;
        float tmp2 = alL * ((t2L - 1.f) * (a * a - b * b)) * inv;
        float tmp3 = alL * alLm1 * (2.f * (Lf - 1.f + a) * (Lf - 1.f + b) * t2L) * inv;
        float nx = tmp1 * accs[m] - tmp2 * bf2f(pr[m * DC]) - tmp3 * xr;
        xs2[(r * MM + m) * DC + lane] = f2bf(nx);
        out2 += wm * nx;
    }
    out[(r * OUT_K + 2) * DF + d0 + lane] = out2;
}

template <int DC>
__global__ __launch_bounds__(256) void k_stage3(
    const int* __restrict__ rowstart, const int* __restrict__ deg,
    const int* __restrict__ ccol, const float* __restrict__ cval,
    const unsigned short* __restrict__ xs2, const unsigned short* __restrict__ xs1,
    const float* __restrict__ alphas, const float* __restrict__ w,
    const float* __restrict__ a_arr, const float* __restrict__ b_arr,
    float* __restrict__ out, int d0) {
    int r = (blockIdx.x * blockDim.x + threadIdx.x) / DC;
    int lane = threadIdx.x & (DC - 1);
    if (r >= NN) return;
    int s = rowstart[r], e = s + deg[r];
    float accs[MM];
    #pragma unroll
    for (int m = 0; m < MM; ++m) accs[m] = 0.f;
    for (int i = s; i < e; ++i) {
        int c = __builtin_nontemporal_load(&ccol[i]);
        float v = __builtin_nontemporal_load(&cval[i]);
        const unsigned short* p = xs2 + c * (MM * DC) + lane;
        #pragma unroll
        for (int m = 0; m < MM; ++m) accs[m] += v * bf2f(p[m * DC]);
    }
    const unsigned short* pr  = xs2 + r * (MM * DC) + lane;
    const unsigned short* pr2 = xs1 + r * (MM * DC) + lane;
    float out3 = 0.f;
    #pragma unroll
    for (int m = 0; m < MM; ++m) {
        float a = a_arr[m], b = b_arr[m];
        float alL = alphas[2 * MM + m], alLm1 = alphas[1 * MM + m];
        float wm = w[m];
        const float Lf = 3.f;
        float ab = a + b;
        float t2L = 2.f * Lf + ab;
        float coef_l = 2.f * Lf * (Lf + ab) * (t2L - 2.f);
        float inv = 1.f / coef_l;
        float tmp1 = alL * ((t2L - 1.f) * t2L * (t2L - 2.f)) * inv;
        float tmp2 = alL * ((t2L - 1.f) * (a * a - b * b)) * inv;
        float tmp3 = alL * alLm1 * (2.f * (Lf - 1.f + a) * (Lf - 1.f + b) * t2L) * inv;
        float nx = tmp1 * accs[m] - tmp2 * bf2f(pr[m * DC]) - tmp3 * bf2f(pr2[m * DC]);
        out3 += wm * nx;
    }
    out[(r * OUT_K + 3) * DF + d0 + lane] = out3;
}

// ---------------- launch ----------------

template <int DC>
static void run_passes(const int* rowstart, const int* deg, const int* ccol,
                       const float* cval, const float* x, const float* alphas,
                       const float* w, const float* a_arr, const float* b_arr,
                       unsigned short* xs1, unsigned short* xs2, float* out,
                       hipStream_t stream) {
    const int rows_per_block = 256 / DC;
    const int blocks = (NN + rows_per_block - 1) / rows_per_block;
    for (int d0 = 0; d0 < DF; d0 += DC) {
        k_stage1<DC><<<blocks, 256, 0, stream>>>(rowstart, deg, ccol, cval, x,
                                                 alphas, w, a_arr, b_arr, xs1, out, d0);
        k_stage2<DC><<<blocks, 256, 0, stream>>>(rowstart, deg, ccol, cval, xs1, x,
                                                 alphas, w, a_arr, b_arr, xs2, out, d0);
        k_stage3<DC><<<blocks, 256, 0, stream>>>(rowstart, deg, ccol, cval, xs2, xs1,
                                                 alphas, w, a_arr, b_arr, out, d0);
    }
}

extern "C" void kernel_launch(void* const* d_in, const int* in_sizes, int n_in,
                              void* d_out, int out_size, void* d_ws, size_t ws_size,
                              hipStream_t stream) {
    const float* x      = (const float*)d_in[0];
    const int*   ei     = (const int*)d_in[1];
    const float* ea     = (const float*)d_in[2];
    const float* alphas = (const float*)d_in[3];
    const float* w      = (const float*)d_in[4];
    const float* a_arr  = (const float*)d_in[5];
    const float* b_arr  = (const float*)d_in[6];
    float* out = (float*)d_out;
    const int* row = ei;
    const int* col = ei + NE;

    char* ws = (char*)d_ws;
    size_t off = 0;
    auto alloc = [&](size_t bytes) {
        void* p = ws + off;
        off = (off + bytes + 255) & ~(size_t)255;
        return p;
    };
    // deg, fill, counter contiguous so one memset zeroes all three
    int* deg      = (int*)alloc((size_t)(2 * NN + 1) * sizeof(int));
    int* fill     = deg + NN;
    int* counter  = deg + 2 * NN;
    int* rowstart = (int*)alloc((size_t)NN * sizeof(int));
    float* dinv   = (float*)alloc((size_t)NN * sizeof(float));
    int* ccol     = (int*)alloc((size_t)NE * sizeof(int));
    float* cval   = (float*)alloc((size_t)NE * sizeof(float));
    size_t fixed_end = off;

    // Largest feature-chunk DC whose two bf16 history tensors fit in ws.
    int DC = 64;
    while (DC > 8) {
        size_t need = fixed_end +
            2 * (((size_t)NN * MM * DC * sizeof(unsigned short) + 255) & ~(size_t)255);
        if (need <= ws_size) break;
        DC >>= 1;
    }
    unsigned short* xs1 = (unsigned short*)alloc((size_t)NN * MM * DC * sizeof(unsigned short));
    unsigned short* xs2 = (unsigned short*)alloc((size_t)NN * MM * DC * sizeof(unsigned short));

    hipMemsetAsync(deg, 0, (size_t)(2 * NN + 1) * sizeof(int), stream);

    k_deg<<<(NE + 255) / 256, 256, 0, stream>>>(row, deg);
    k_alloc<<<(NN + 255) / 256, 256, 0, stream>>>(deg, counter, rowstart);
    k_dinv<<<(NN + 255) / 256, 256, 0, stream>>>(deg, dinv);
    k_fill<<<(NE + 255) / 256, 256, 0, stream>>>(row, col, ea, dinv, rowstart, fill,
                                                 ccol, cval);

    switch (DC) {
        case 64: run_passes<64>(rowstart, deg, ccol, cval, x, alphas, w, a_arr, b_arr,
                                xs1, xs2, out, stream); break;
        case 32: run_passes<32>(rowstart, deg, ccol, cval, x, alphas, w, a_arr, b_arr,
                                xs1, xs2, out, stream); break;
        case 16: run_passes<16>(rowstart, deg, ccol, cval, x, alphas, w, a_arr, b_arr,
                                xs1, xs2, out, stream); break;
        default: run_passes<8>(rowstart, deg, ccol, cval, x, alphas, w, a_arr, b_arr,
                               xs1, xs2, out, stream); break;
    }
}

// Round 5
// 686.206 us; speedup vs baseline: 1.4139x; 1.0027x over previous
//
#include <hip/hip_runtime.h>

#define NN 50000      // nodes
#define NE 800000     // edges
#define DF 64         // features
#define MM 11         // (a,b) tuples
#define MP 12         // m padded to 12 (24 B/lane -> 3x dwordx2)
#define OUT_K 4       // DEPTH+1 output planes

__device__ __forceinline__ float bflo(unsigned int d) {
    union { unsigned int i; float f; } v; v.i = d << 16; return v.f;
}
__device__ __forceinline__ float bfhi(unsigned int d) {
    union { unsigned int i; float f; } v; v.i = d & 0xFFFF0000u; return v.f;
}
__device__ __forceinline__ float bf2f(unsigned short u) {
    union { unsigned int i; float f; } v; v.i = ((unsigned int)u) << 16; return v.f;
}
__device__ __forceinline__ unsigned short f2bf(float f) {
    union { float f; unsigned int i; } v; v.f = f;
    unsigned int u = v.i + 0x7FFFu + ((v.i >> 16) & 1u);
    return (unsigned short)(u >> 16);
}
__device__ __forceinline__ unsigned int pk2(float lo, float hi) {
    return (unsigned int)f2bf(lo) | ((unsigned int)f2bf(hi) << 16);
}

// ---------------- CSR build ----------------

__global__ void k_deg(const int* __restrict__ row, int* __restrict__ deg) {
    int e = blockIdx.x * blockDim.x + threadIdx.x;
    if (e < NE) atomicAdd(&deg[row[e]], 1);
}

__global__ void k_alloc(const int* __restrict__ deg, int* __restrict__ counter,
                        int* __restrict__ rowstart) {
    int i = blockIdx.x * blockDim.x + threadIdx.x;
    int lane = threadIdx.x & 63;
    int d = (i < NN) ? deg[i] : 0;
    int v = d;
    #pragma unroll
    for (int off = 1; off < 64; off <<= 1) {
        int t = __shfl_up(v, off, 64);
        if (lane >= off) v += t;
    }
    int total = __shfl(v, 63, 64);
    int base = 0;
    if (lane == 63) base = atomicAdd(counter, total);
    base = __shfl(base, 63, 64);
    if (i < NN) rowstart[i] = base + v - d;
}

__global__ void k_dinv(const int* __restrict__ deg, float* __restrict__ dinv) {
    int i = blockIdx.x * blockDim.x + threadIdx.x;
    if (i < NN) {
        int d = deg[i];
        dinv[i] = 1.0f / sqrtf((float)(d == 0 ? 1 : d));
    }
}

// fused edge record: low32 = col, high32 = fp32 weight bits
__global__ void k_fill(const int* __restrict__ row, const int* __restrict__ col,
                       const float* __restrict__ ea, const float* __restrict__ dinv,
                       const int* __restrict__ rowstart, int* __restrict__ fill,
                       unsigned long long* __restrict__ ecv) {
    int e = blockIdx.x * blockDim.x + threadIdx.x;
    if (e < NE) {
        int r = row[e], c = col[e];
        int pos = rowstart[r] + atomicAdd(&fill[r], 1);
        float v = dinv[r] * ea[e] * dinv[c];
        unsigned long long rec = (unsigned long long)(unsigned int)c |
            ((unsigned long long)__float_as_uint(v) << 32);
        ecv[pos] = rec;
    }
}

// bf16 copy of x for the stage-1 gather (halves stage-1 gather bytes)
__global__ void k_cast(const float* __restrict__ x, unsigned short* __restrict__ xb) {
    int i = blockIdx.x * blockDim.x + threadIdx.x;
    if (i < NN * DF) xb[i] = f2bf(x[i]);
}

// ---------------- packed-row helpers ----------------
// xs layout: (node, dchunk(DC), m(MP)) bf16; node stride DC*MP elements.
// Lane owns 24 contiguous bytes -> 3x uint2 (8B-aligned).

template <int DC>
__device__ __forceinline__ void load12(const unsigned short* __restrict__ base,
                                       int node, int lane, float* f) {
    const uint2* q = (const uint2*)(base + (size_t)node * (DC * MP)) + lane * 3;
    uint2 u0 = q[0], u1 = q[1], u2 = q[2];
    f[0] = bflo(u0.x);  f[1] = bfhi(u0.x);
    f[2] = bflo(u0.y);  f[3] = bfhi(u0.y);
    f[4] = bflo(u1.x);  f[5] = bfhi(u1.x);
    f[6] = bflo(u1.y);  f[7] = bfhi(u1.y);
    f[8] = bflo(u2.x);  f[9] = bfhi(u2.x);
    f[10] = bflo(u2.y);
}

template <int DC>
__device__ __forceinline__ void store12(unsigned short* __restrict__ base,
                                        int node, int lane, const float* f) {
    uint2* q = (uint2*)(base + (size_t)node * (DC * MP)) + lane * 3;
    uint2 u0, u1, u2;
    u0.x = pk2(f[0], f[1]);  u0.y = pk2(f[2], f[3]);
    u1.x = pk2(f[4], f[5]);  u1.y = pk2(f[6], f[7]);
    u2.x = pk2(f[8], f[9]);  u2.y = pk2(f[10], 0.f);
    q[0] = u0; q[1] = u1; q[2] = u2;
}

// ---------------- Stage kernels ----------------

template <int DC>
__global__ __launch_bounds__(256) void k_stage1(
    const int* __restrict__ rowstart, const int* __restrict__ deg,
    const unsigned long long* __restrict__ ecv, const unsigned short* __restrict__ xb,
    const float* __restrict__ x, const float* __restrict__ alphas,
    const float* __restrict__ w, const float* __restrict__ a_arr,
    const float* __restrict__ b_arr,
    unsigned short* __restrict__ xs1, float* __restrict__ out, int d0) {
    int r = (blockIdx.x * blockDim.x + threadIdx.x) / DC;
    int lane = threadIdx.x & (DC - 1);
    if (r >= NN) return;
    int s = rowstart[r], e = s + deg[r];
    float acc = 0.f;
    for (int i = s; i < e; ++i) {
        unsigned long long ec = __builtin_nontemporal_load(&ecv[i]);
        int c = (int)(unsigned int)(ec & 0xFFFFFFFFull);
        float v = __uint_as_float((unsigned int)(ec >> 32));
        acc += v * bf2f(xb[c * DF + d0 + lane]);
    }
    float xr = x[r * DF + d0 + lane];
    float vals[MM + 1];
    float out1 = 0.f, wsum = 0.f;
    #pragma unroll
    for (int m = 0; m < MM; ++m) {
        float a = a_arr[m], b = b_arr[m];
        float al0 = alphas[m];
        float wm = w[m];
        float c1 = 0.5f * (a - b);
        float c2 = 0.5f * (a + b + 2.f);
        float v = al0 * (c1 * xr + c2 * acc);
        vals[m] = v;
        out1 += wm * v;
        wsum += wm;
    }
    store12<DC>(xs1, r, lane, vals);
    out[(r * OUT_K + 0) * DF + d0 + lane] = wsum * xr;
    out[(r * OUT_K + 1) * DF + d0 + lane] = out1;
}

template <int DC>
__global__ __launch_bounds__(256) void k_stage2(
    const int* __restrict__ rowstart, const int* __restrict__ deg,
    const unsigned long long* __restrict__ ecv, const unsigned short* __restrict__ xs1,
    const float* __restrict__ x, const float* __restrict__ alphas,
    const float* __restrict__ w, const float* __restrict__ a_arr,
    const float* __restrict__ b_arr,
    unsigned short* __restrict__ xs2, float* __restrict__ out, int d0) {
    int r = (blockIdx.x * blockDim.x + threadIdx.x) / DC;
    int lane = threadIdx.x & (DC - 1);
    if (r >= NN) return;
    int s = rowstart[r], e = s + deg[r];
    float a0 = 0.f, a1 = 0.f, a2 = 0.f, a3 = 0.f, a4 = 0.f, a5 = 0.f,
          a6 = 0.f, a7 = 0.f, a8 = 0.f, a9 = 0.f, a10 = 0.f;
    for (int i = s; i < e; ++i) {
        unsigned long long ec = __builtin_nontemporal_load(&ecv[i]);
        int c = (int)(unsigned int)(ec & 0xFFFFFFFFull);
        float v = __uint_as_float((unsigned int)(ec >> 32));
        const uint2* q = (const uint2*)(xs1 + (size_t)c * (DC * MP)) + lane * 3;
        uint2 u0 = q[0], u1 = q[1], u2 = q[2];
        a0 += v * bflo(u0.x);  a1 += v * bfhi(u0.x);
        a2 += v * bflo(u0.y);  a3 += v * bfhi(u0.y);
        a4 += v * bflo(u1.x);  a5 += v * bfhi(u1.x);
        a6 += v * bflo(u1.y);  a7 += v * bfhi(u1.y);
        a8 += v * bflo(u2.x);  a9 += v * bfhi(u2.x);
        a10 += v * bflo(u2.y);
    }
    float accs[MM] = {a0, a1, a2, a3, a4, a5, a6, a7, a8, a9, a10};
    float xr = x[r * DF + d0 + lane];
    float prf[MM + 1];
    load12<DC>(xs1, r, lane, prf);
    float vals[MM + 1];
    float out2 = 0.f;
    #pragma unroll
    for (int m = 0; m < MM; ++m) {
        float a = a_arr[m], b = b_arr[m];
        float alL = alphas[1 * MM + m], alLm1 = alphas[0 * MM + m];
        float wm = w[m];
        const float Lf = 2.f;
        float ab = a + b;
        float t2L = 2.f * Lf + ab;
        float coef_l = 2.f * Lf * (Lf + ab) * (t2L - 2.f);
        float inv = 1.f / coef_l;
        float tmp1 = alL * ((t2L - 1.f) * t2L * (t2L - 2.f)) * inv;
        float tmp2 = alL * ((t2L - 1.f) * (a * a - b * b)) * inv;
        float tmp3 = alL * alLm1 * (2.f * (Lf - 1.f + a) * (Lf - 1.f + b) * t2L) * inv;
        float nx = tmp1 * accs[m] - tmp2 * prf[m] - tmp3 * xr;
        vals[m] = nx;
        out2 += wm * nx;
    }
    store12<DC>(xs2, r, lane, vals);
    out[(r * OUT_K + 2) * DF + d0 + lane] = out2;
}

template <int DC>
__global__ __launch_bounds__(256) void k_stage3(
    const int* __restrict__ rowstart, const int* __restrict__ deg,
    const unsigned long long* __restrict__ ecv, const unsigned short* __restrict__ xs2,
    const unsigned short* __restrict__ xs1, const float* __restrict__ alphas,
    const float* __restrict__ w, const float* __restrict__ a_arr,
    const float* __restrict__ b_arr,
    float* __restrict__ out, int d0) {
    int r = (blockIdx.x * blockDim.x + threadIdx.x) / DC;
    int lane = threadIdx.x & (DC - 1);
    if (r >= NN) return;
    int s = rowstart[r], e = s + deg[r];
    float a0 = 0.f, a1 = 0.f, a2 = 0.f, a3 = 0.f, a4 = 0.f, a5 = 0.f,
          a6 = 0.f, a7 = 0.f, a8 = 0.f, a9 = 0.f, a10 = 0.f;
    for (int i = s; i < e; ++i) {
        unsigned long long ec = __builtin_nontemporal_load(&ecv[i]);
        int c = (int)(unsigned int)(ec & 0xFFFFFFFFull);
        float v = __uint_as_float((unsigned int)(ec >> 32));
        const uint2* q = (const uint2*)(xs2 + (size_t)c * (DC * MP)) + lane * 3;
        uint2 u0 = q[0], u1 = q[1], u2 = q[2];
        a0 += v * bflo(u0.x);  a1 += v * bfhi(u0.x);
        a2 += v * bflo(u0.y);  a3 += v * bfhi(u0.y);
        a4 += v * bflo(u1.x);  a5 += v * bfhi(u1.x);
        a6 += v * bflo(u1.y);  a7 += v * bfhi(u1.y);
        a8 += v * bflo(u2.x);  a9 += v * bfhi(u2.x);
        a10 += v * bflo(u2.y);
    }
    float accs[MM] = {a0, a1, a2, a3, a4, a5, a6, a7, a8, a9, a10};
    float prf[MM + 1], pr2f[MM + 1];
    load12<DC>(xs2, r, lane, prf);
    load12<DC>(xs1, r, lane, pr2f);
    float out3 = 0.f;
    #pragma unroll
    for (int m = 0; m < MM; ++m) {
        float a = a_arr[m], b = b_arr[m];
        float alL = alphas[2 * MM + m], alLm1 = alphas[1 * MM + m];
        float wm = w[m];
        const float Lf = 3.f;
        float ab = a + b;
        float t2L = 2.f * Lf + ab;
        float coef_l = 2.f * Lf * (Lf + ab) * (t2L - 2.f);
        float inv = 1.f / coef_l;
        float tmp1 = alL * ((t2L - 1.f) * t2L * (t2L - 2.f)) * inv;
        float tmp2 = alL * ((t2L - 1.f) * (a * a - b * b)) * inv;
        float tmp3 = alL * alLm1 * (2.f * (Lf - 1.f + a) * (Lf - 1.f + b) * t2L) * inv;
        float nx = tmp1 * accs[m] - tmp2 * prf[m] - tmp3 * pr2f[m];
        out3 += wm * nx;
    }
    out[(r * OUT_K + 3) * DF + d0 + lane] = out3;
}

// ---------------- launch ----------------

template <int DC>
static void run_passes(const int* rowstart, const int* deg, const unsigned long long* ecv,
                       const unsigned short* xb, const float* x, const float* alphas,
                       const float* w, const float* a_arr, const float* b_arr,
                       unsigned short* xs1, unsigned short* xs2, float* out,
                       hipStream_t stream) {
    const int rows_per_block = 256 / DC;
    const int blocks = (NN + rows_per_block - 1) / rows_per_block;
    for (int d0 = 0; d0 < DF; d0 += DC) {
        k_stage1<DC><<<blocks, 256, 0, stream>>>(rowstart, deg, ecv, xb, x, alphas,
                                                 w, a_arr, b_arr, xs1, out, d0);
        k_stage2<DC><<<blocks, 256, 0, stream>>>(rowstart, deg, ecv, xs1, x, alphas,
                                                 w, a_arr, b_arr, xs2, out, d0);
        k_stage3<DC><<<blocks, 256, 0, stream>>>(rowstart, deg, ecv, xs2, xs1,
                                                 alphas, w, a_arr, b_arr, out, d0);
    }
}

extern "C" void kernel_launch(void* const* d_in, const int* in_sizes, int n_in,
                              void* d_out, int out_size, void* d_ws, size_t ws_size,
                              hipStream_t stream) {
    const float* x      = (const float*)d_in[0];
    const int*   ei     = (const int*)d_in[1];
    const float* ea     = (const float*)d_in[2];
    const float* alphas = (const float*)d_in[3];
    const float* w      = (const float*)d_in[4];
    const float* a_arr  = (const float*)d_in[5];
    const float* b_arr  = (const float*)d_in[6];
    float* out = (float*)d_out;
    const int* row = ei;
    const int* col = ei + NE;

    char* ws = (char*)d_ws;
    size_t off = 0;
    auto alloc = [&](size_t bytes) {
        void* p = ws + off;
        off = (off + bytes + 255) & ~(size_t)255;
        return p;
    };
    // deg, fill, counter contiguous so one memset zeroes all three
    int* deg      = (int*)alloc((size_t)(2 * NN + 1) * sizeof(int));
    int* fill     = deg + NN;
    int* counter  = deg + 2 * NN;
    int* rowstart = (int*)alloc((size_t)NN * sizeof(int));
    float* dinv   = (float*)alloc((size_t)NN * sizeof(float));
    unsigned long long* ecv =
        (unsigned long long*)alloc((size_t)NE * sizeof(unsigned long long));
    unsigned short* xb = (unsigned short*)alloc((size_t)NN * DF * sizeof(unsigned short));
    size_t fixed_end = off;

    // Largest feature-chunk DC whose two packed bf16 history tensors fit.
    int DC = 64;
    while (DC > 8) {
        size_t need = fixed_end +
            2 * (((size_t)NN * DC * MP * sizeof(unsigned short) + 255) & ~(size_t)255);
        if (need <= ws_size) break;
        DC >>= 1;
    }
    unsigned short* xs1 = (unsigned short*)alloc((size_t)NN * DC * MP * sizeof(unsigned short));
    unsigned short* xs2 = (unsigned short*)alloc((size_t)NN * DC * MP * sizeof(unsigned short));

    (void)hipMemsetAsync(deg, 0, (size_t)(2 * NN + 1) * sizeof(int), stream);

    k_deg<<<(NE + 255) / 256, 256, 0, stream>>>(row, deg);
    k_alloc<<<(NN + 255) / 256, 256, 0, stream>>>(deg, counter, rowstart);
    k_dinv<<<(NN + 255) / 256, 256, 0, stream>>>(deg, dinv);
    k_fill<<<(NE + 255) / 256, 256, 0, stream>>>(row, col, ea, dinv, rowstart, fill, ecv);
    k_cast<<<(NN * DF + 255) / 256, 256, 0, stream>>>(x, xb);

    switch (DC) {
        case 64: run_passes<64>(rowstart, deg, ecv, xb, x, alphas, w, a_arr, b_arr,
                                xs1, xs2, out, stream); break;
        case 32: run_passes<32>(rowstart, deg, ecv, xb, x, alphas, w, a_arr, b_arr,
                                xs1, xs2, out, stream); break;
        case 16: run_passes<16>(rowstart, deg, ecv, xb, x, alphas, w, a_arr, b_arr,
                                xs1, xs2, out, stream); break;
        default: run_passes<8>(rowstart, deg, ecv, xb, x, alphas, w, a_arr, b_arr,
                               xs1, xs2, out, stream); break;
    }
}

// Round 6
// 614.478 us; speedup vs baseline: 1.5789x; 1.1167x over previous
//
#include <hip/hip_runtime.h>

#define NN 50000      // nodes
#define NE 800000     // edges
#define DF 64         // features
#define MM 11         // (a,b) tuples
#define MP 12         // m padded to 12 (24 B/lane -> 3x dwordx2)
#define OUT_K 4       // DEPTH+1 output planes

__device__ __forceinline__ float bflo(unsigned int d) {
    union { unsigned int i; float f; } v; v.i = d << 16; return v.f;
}
__device__ __forceinline__ float bfhi(unsigned int d) {
    union { unsigned int i; float f; } v; v.i = d & 0xFFFF0000u; return v.f;
}
__device__ __forceinline__ float bf2f(unsigned short u) {
    union { unsigned int i; float f; } v; v.i = ((unsigned int)u) << 16; return v.f;
}
__device__ __forceinline__ unsigned short f2bf(float f) {
    union { float f; unsigned int i; } v; v.f = f;
    unsigned int u = v.i + 0x7FFFu + ((v.i >> 16) & 1u);
    return (unsigned short)(u >> 16);
}
__device__ __forceinline__ unsigned int pk2(float lo, float hi) {
    return (unsigned int)f2bf(lo) | ((unsigned int)f2bf(hi) << 16);
}

// ---------------- CSR build ----------------

__global__ void k_deg(const int* __restrict__ row, int* __restrict__ deg) {
    int e = blockIdx.x * blockDim.x + threadIdx.x;
    if (e < NE) atomicAdd(&deg[row[e]], 1);
}

// slab alloc (wave scan + one atomic/wave) + dinv fused
__global__ void k_alloc(const int* __restrict__ deg, int* __restrict__ counter,
                        int* __restrict__ rowstart, float* __restrict__ dinv) {
    int i = blockIdx.x * blockDim.x + threadIdx.x;
    int lane = threadIdx.x & 63;
    int d = (i < NN) ? deg[i] : 0;
    int v = d;
    #pragma unroll
    for (int off = 1; off < 64; off <<= 1) {
        int t = __shfl_up(v, off, 64);
        if (lane >= off) v += t;
    }
    int total = __shfl(v, 63, 64);
    int base = 0;
    if (lane == 63) base = atomicAdd(counter, total);
    base = __shfl(base, 63, 64);
    if (i < NN) {
        rowstart[i] = base + v - d;
        dinv[i] = 1.0f / sqrtf((float)(d == 0 ? 1 : d));
    }
}

// fused edge record: low32 = col, high32 = fp32 weight bits
__global__ void k_fill(const int* __restrict__ row, const int* __restrict__ col,
                       const float* __restrict__ ea, const float* __restrict__ dinv,
                       const int* __restrict__ rowstart, int* __restrict__ fill,
                       unsigned long long* __restrict__ ecv) {
    int e = blockIdx.x * blockDim.x + threadIdx.x;
    if (e < NE) {
        int r = row[e], c = col[e];
        int pos = rowstart[r] + atomicAdd(&fill[r], 1);
        float v = dinv[r] * ea[e] * dinv[c];
        unsigned long long rec = (unsigned long long)(unsigned int)c |
            ((unsigned long long)__float_as_uint(v) << 32);
        ecv[pos] = rec;
    }
}

// bf16 copy of x for the stage-1 gather
__global__ void k_cast(const float* __restrict__ x, unsigned short* __restrict__ xb) {
    int i = blockIdx.x * blockDim.x + threadIdx.x;
    if (i < NN * DF) xb[i] = f2bf(x[i]);
}

// ---------------- packed-row helpers ----------------

template <int DC>
__device__ __forceinline__ void load12(const unsigned short* __restrict__ base,
                                       int node, int lane, float* f) {
    const uint2* q = (const uint2*)(base + (size_t)node * (DC * MP)) + lane * 3;
    uint2 u0 = q[0], u1 = q[1], u2 = q[2];
    f[0] = bflo(u0.x);  f[1] = bfhi(u0.x);
    f[2] = bflo(u0.y);  f[3] = bfhi(u0.y);
    f[4] = bflo(u1.x);  f[5] = bfhi(u1.x);
    f[6] = bflo(u1.y);  f[7] = bfhi(u1.y);
    f[8] = bflo(u2.x);  f[9] = bfhi(u2.x);
    f[10] = bflo(u2.y);
}

template <int DC>
__device__ __forceinline__ void store12(unsigned short* __restrict__ base,
                                        int node, int lane, const float* f) {
    uint2* q = (uint2*)(base + (size_t)node * (DC * MP)) + lane * 3;
    uint2 u0, u1, u2;
    u0.x = pk2(f[0], f[1]);  u0.y = pk2(f[2], f[3]);
    u1.x = pk2(f[4], f[5]);  u1.y = pk2(f[6], f[7]);
    u2.x = pk2(f[8], f[9]);  u2.y = pk2(f[10], 0.f);
    q[0] = u0; q[1] = u1; q[2] = u2;
}

// ---------------- Stage kernels ----------------
// Gather loops are batched (CH edges) to keep many loads in flight per wave:
// load CH independent edge records, issue all gathers, then accumulate.

template <int DC>
__global__ __launch_bounds__(256) void k_stage1(
    const int* __restrict__ rowstart, const int* __restrict__ deg,
    const unsigned long long* __restrict__ ecv, const unsigned short* __restrict__ xb,
    const float* __restrict__ x, const float* __restrict__ alphas,
    const float* __restrict__ w, const float* __restrict__ a_arr,
    const float* __restrict__ b_arr,
    unsigned short* __restrict__ xs1, float* __restrict__ out, int d0) {
    int r = (blockIdx.x * blockDim.x + threadIdx.x) / DC;
    int lane = threadIdx.x & (DC - 1);
    if (r >= NN) return;
    int s = rowstart[r], e = s + deg[r];
    float acc = 0.f;
    const int CH = 8;
    int i = s;
    for (; i + CH <= e; i += CH) {
        unsigned long long ec[CH];
        #pragma unroll
        for (int j = 0; j < CH; ++j) ec[j] = __builtin_nontemporal_load(&ecv[i + j]);
        unsigned short g[CH];
        float vv[CH];
        #pragma unroll
        for (int j = 0; j < CH; ++j) {
            int c = (int)(unsigned int)(ec[j] & 0xFFFFFFFFull);
            vv[j] = __uint_as_float((unsigned int)(ec[j] >> 32));
            g[j] = xb[c * DF + d0 + lane];
        }
        #pragma unroll
        for (int j = 0; j < CH; ++j) acc += vv[j] * bf2f(g[j]);
    }
    for (; i < e; ++i) {
        unsigned long long ec = __builtin_nontemporal_load(&ecv[i]);
        int c = (int)(unsigned int)(ec & 0xFFFFFFFFull);
        float v = __uint_as_float((unsigned int)(ec >> 32));
        acc += v * bf2f(xb[c * DF + d0 + lane]);
    }
    float xr = x[r * DF + d0 + lane];
    float vals[MM + 1];
    float out1 = 0.f, wsum = 0.f;
    #pragma unroll
    for (int m = 0; m < MM; ++m) {
        float a = a_arr[m], b = b_arr[m];
        float al0 = alphas[m];
        float wm = w[m];
        float c1 = 0.5f * (a - b);
        float c2 = 0.5f * (a + b + 2.f);
        float v = al0 * (c1 * xr + c2 * acc);
        vals[m] = v;
        out1 += wm * v;
        wsum += wm;
    }
    store12<DC>(xs1, r, lane, vals);
    out[(r * OUT_K + 0) * DF + d0 + lane] = wsum * xr;
    out[(r * OUT_K + 1) * DF + d0 + lane] = out1;
}

// shared batched gather body for stages 2/3
template <int DC>
__device__ __forceinline__ void gather_accum(
    const unsigned long long* __restrict__ ecv, int s, int e,
    const unsigned short* __restrict__ xs, int lane, float* accs) {
    float a0 = 0.f, a1 = 0.f, a2 = 0.f, a3 = 0.f, a4 = 0.f, a5 = 0.f,
          a6 = 0.f, a7 = 0.f, a8 = 0.f, a9 = 0.f, a10 = 0.f;
    const int CH = 4;
    int i = s;
    for (; i + CH <= e; i += CH) {
        unsigned long long ec[CH];
        #pragma unroll
        for (int j = 0; j < CH; ++j) ec[j] = __builtin_nontemporal_load(&ecv[i + j]);
        uint2 g[CH][3];
        float vv[CH];
        #pragma unroll
        for (int j = 0; j < CH; ++j) {
            int c = (int)(unsigned int)(ec[j] & 0xFFFFFFFFull);
            vv[j] = __uint_as_float((unsigned int)(ec[j] >> 32));
            const uint2* q = (const uint2*)(xs + (size_t)c * (DC * MP)) + lane * 3;
            g[j][0] = q[0]; g[j][1] = q[1]; g[j][2] = q[2];
        }
        #pragma unroll
        for (int j = 0; j < CH; ++j) {
            float v = vv[j];
            a0 += v * bflo(g[j][0].x);  a1 += v * bfhi(g[j][0].x);
            a2 += v * bflo(g[j][0].y);  a3 += v * bfhi(g[j][0].y);
            a4 += v * bflo(g[j][1].x);  a5 += v * bfhi(g[j][1].x);
            a6 += v * bflo(g[j][1].y);  a7 += v * bfhi(g[j][1].y);
            a8 += v * bflo(g[j][2].x);  a9 += v * bfhi(g[j][2].x);
            a10 += v * bflo(g[j][2].y);
        }
    }
    for (; i < e; ++i) {
        unsigned long long ec = __builtin_nontemporal_load(&ecv[i]);
        int c = (int)(unsigned int)(ec & 0xFFFFFFFFull);
        float v = __uint_as_float((unsigned int)(ec >> 32));
        const uint2* q = (const uint2*)(xs + (size_t)c * (DC * MP)) + lane * 3;
        uint2 u0 = q[0], u1 = q[1], u2 = q[2];
        a0 += v * bflo(u0.x);  a1 += v * bfhi(u0.x);
        a2 += v * bflo(u0.y);  a3 += v * bfhi(u0.y);
        a4 += v * bflo(u1.x);  a5 += v * bfhi(u1.x);
        a6 += v * bflo(u1.y);  a7 += v * bfhi(u1.y);
        a8 += v * bflo(u2.x);  a9 += v * bfhi(u2.x);
        a10 += v * bflo(u2.y);
    }
    accs[0] = a0; accs[1] = a1; accs[2] = a2; accs[3] = a3; accs[4] = a4;
    accs[5] = a5; accs[6] = a6; accs[7] = a7; accs[8] = a8; accs[9] = a9;
    accs[10] = a10;
}

template <int DC>
__global__ __launch_bounds__(256) void k_stage2(
    const int* __restrict__ rowstart, const int* __restrict__ deg,
    const unsigned long long* __restrict__ ecv, const unsigned short* __restrict__ xs1,
    const float* __restrict__ x, const float* __restrict__ alphas,
    const float* __restrict__ w, const float* __restrict__ a_arr,
    const float* __restrict__ b_arr,
    unsigned short* __restrict__ xs2, float* __restrict__ out, int d0) {
    int r = (blockIdx.x * blockDim.x + threadIdx.x) / DC;
    int lane = threadIdx.x & (DC - 1);
    if (r >= NN) return;
    int s = rowstart[r], e = s + deg[r];
    float accs[MM];
    gather_accum<DC>(ecv, s, e, xs1, lane, accs);
    float xr = x[r * DF + d0 + lane];
    float prf[MM + 1];
    load12<DC>(xs1, r, lane, prf);
    float vals[MM + 1];
    float out2 = 0.f;
    #pragma unroll
    for (int m = 0; m < MM; ++m) {
        float a = a_arr[m], b = b_arr[m];
        float alL = alphas[1 * MM + m], alLm1 = alphas[0 * MM + m];
        float wm = w[m];
        const float Lf = 2.f;
        float ab = a + b;
        float t2L = 2.f * Lf + ab;
        float coef_l = 2.f * Lf * (Lf + ab) * (t2L - 2.f);
        float inv = 1.f / coef_l;
        float tmp1 = alL * ((t2L - 1.f) * t2L * (t2L - 2.f)) * inv;
        float tmp2 = alL * ((t2L - 1.f) * (a * a - b * b)) * inv;
        float tmp3 = alL * alLm1 * (2.f * (Lf - 1.f + a) * (Lf - 1.f + b) * t2L) * inv;
        float nx = tmp1 * accs[m] - tmp2 * prf[m] - tmp3 * xr;
        vals[m] = nx;
        out2 += wm * nx;
    }
    store12<DC>(xs2, r, lane, vals);
    out[(r * OUT_K + 2) * DF + d0 + lane] = out2;
}

template <int DC>
__global__ __launch_bounds__(256) void k_stage3(
    const int* __restrict__ rowstart, const int* __restrict__ deg,
    const unsigned long long* __restrict__ ecv, const unsigned short* __restrict__ xs2,
    const unsigned short* __restrict__ xs1, const float* __restrict__ alphas,
    const float* __restrict__ w, const float* __restrict__ a_arr,
    const float* __restrict__ b_arr,
    float* __restrict__ out, int d0) {
    int r = (blockIdx.x * blockDim.x + threadIdx.x) / DC;
    int lane = threadIdx.x & (DC - 1);
    if (r >= NN) return;
    int s = rowstart[r], e = s + deg[r];
    float accs[MM];
    gather_accum<DC>(ecv, s, e, xs2, lane, accs);
    float prf[MM + 1], pr2f[MM + 1];
    load12<DC>(xs2, r, lane, prf);
    load12<DC>(xs1, r, lane, pr2f);
    float out3 = 0.f;
    #pragma unroll
    for (int m = 0; m < MM; ++m) {
        float a = a_arr[m], b = b_arr[m];
        float alL = alphas[2 * MM + m], alLm1 = alphas[1 * MM + m];
        float wm = w[m];
        const float Lf = 3.f;
        float ab = a + b;
        float t2L = 2.f * Lf + ab;
        float coef_l = 2.f * Lf * (Lf + ab) * (t2L - 2.f);
        float inv = 1.f / coef_l;
        float tmp1 = alL * ((t2L - 1.f) * t2L * (t2L - 2.f)) * inv;
        float tmp2 = alL * ((t2L - 1.f) * (a * a - b * b)) * inv;
        float tmp3 = alL * alLm1 * (2.f * (Lf - 1.f + a) * (Lf - 1.f + b) * t2L) * inv;
        float nx = tmp1 * accs[m] - tmp2 * prf[m] - tmp3 * pr2f[m];
        out3 += wm * nx;
    }
    out[(r * OUT_K + 3) * DF + d0 + lane] = out3;
}

// ---------------- launch ----------------

template <int DC>
static void run_passes(const int* rowstart, const int* deg, const unsigned long long* ecv,
                       const unsigned short* xb, const float* x, const float* alphas,
                       const float* w, const float* a_arr, const float* b_arr,
                       unsigned short* xs1, unsigned short* xs2, float* out,
                       hipStream_t stream) {
    const int rows_per_block = 256 / DC;
    const int blocks = (NN + rows_per_block - 1) / rows_per_block;
    for (int d0 = 0; d0 < DF; d0 += DC) {
        k_stage1<DC><<<blocks, 256, 0, stream>>>(rowstart, deg, ecv, xb, x, alphas,
                                                 w, a_arr, b_arr, xs1, out, d0);
        k_stage2<DC><<<blocks, 256, 0, stream>>>(rowstart, deg, ecv, xs1, x, alphas,
                                                 w, a_arr, b_arr, xs2, out, d0);
        k_stage3<DC><<<blocks, 256, 0, stream>>>(rowstart, deg, ecv, xs2, xs1,
                                                 alphas, w, a_arr, b_arr, out, d0);
    }
}

extern "C" void kernel_launch(void* const* d_in, const int* in_sizes, int n_in,
                              void* d_out, int out_size, void* d_ws, size_t ws_size,
                              hipStream_t stream) {
    const float* x      = (const float*)d_in[0];
    const int*   ei     = (const int*)d_in[1];
    const float* ea     = (const float*)d_in[2];
    const float* alphas = (const float*)d_in[3];
    const float* w      = (const float*)d_in[4];
    const float* a_arr  = (const float*)d_in[5];
    const float* b_arr  = (const float*)d_in[6];
    float* out = (float*)d_out;
    const int* row = ei;
    const int* col = ei + NE;

    char* ws = (char*)d_ws;
    size_t off = 0;
    auto alloc = [&](size_t bytes) {
        void* p = ws + off;
        off = (off + bytes + 255) & ~(size_t)255;
        return p;
    };
    int* deg      = (int*)alloc((size_t)(2 * NN + 1) * sizeof(int));
    int* fill     = deg + NN;
    int* counter  = deg + 2 * NN;
    int* rowstart = (int*)alloc((size_t)NN * sizeof(int));
    float* dinv   = (float*)alloc((size_t)NN * sizeof(float));
    unsigned long long* ecv =
        (unsigned long long*)alloc((size_t)NE * sizeof(unsigned long long));
    unsigned short* xb = (unsigned short*)alloc((size_t)NN * DF * sizeof(unsigned short));
    size_t fixed_end = off;

    int DC = 64;
    while (DC > 8) {
        size_t need = fixed_end +
            2 * (((size_t)NN * DC * MP * sizeof(unsigned short) + 255) & ~(size_t)255);
        if (need <= ws_size) break;
        DC >>= 1;
    }
    unsigned short* xs1 = (unsigned short*)alloc((size_t)NN * DC * MP * sizeof(unsigned short));
    unsigned short* xs2 = (unsigned short*)alloc((size_t)NN * DC * MP * sizeof(unsigned short));

    (void)hipMemsetAsync(deg, 0, (size_t)(2 * NN + 1) * sizeof(int), stream);

    k_deg<<<(NE + 255) / 256, 256, 0, stream>>>(row, deg);
    k_alloc<<<(NN + 255) / 256, 256, 0, stream>>>(deg, counter, rowstart, dinv);
    k_fill<<<(NE + 255) / 256, 256, 0, stream>>>(row, col, ea, dinv, rowstart, fill, ecv);
    k_cast<<<(NN * DF + 255) / 256, 256, 0, stream>>>(x, xb);

    switch (DC) {
        case 64: run_passes<64>(rowstart, deg, ecv, xb, x, alphas, w, a_arr, b_arr,
                                xs1, xs2, out, stream); break;
        case 32: run_passes<32>(rowstart, deg, ecv, xb, x, alphas, w, a_arr, b_arr,
                                xs1, xs2, out, stream); break;
        case 16: run_passes<16>(rowstart, deg, ecv, xb, x, alphas, w, a_arr, b_arr,
                                xs1, xs2, out, stream); break;
        default: run_passes<8>(rowstart, deg, ecv, xb, x, alphas, w, a_arr, b_arr,
                               xs1, xs2, out, stream); break;
    }
}

// Round 7
// 343.305 us; speedup vs baseline: 2.8261x; 1.7899x over previous
//
#include <hip/hip_runtime.h>

#define NN 50000      // nodes
#define NE 800000     // edges
#define DF 64         // features
#define MM 11         // (a,b) tuples
#define OUT_K 4       // DEPTH+1 output planes

typedef unsigned long long ull;

__device__ __forceinline__ float bf2f(unsigned short u) {
    union { unsigned int i; float f; } v; v.i = ((unsigned int)u) << 16; return v.f;
}
__device__ __forceinline__ unsigned short f2bf(float f) {
    union { float f; unsigned int i; } v; v.f = f;
    unsigned int u = v.i + 0x7FFFu + ((v.i >> 16) & 1u);
    return (unsigned short)(u >> 16);
}

// ---------------- CSR build ----------------

__global__ void k_deg(const int* __restrict__ row, int* __restrict__ deg) {
    int e = blockIdx.x * blockDim.x + threadIdx.x;
    if (e < NE) atomicAdd(&deg[row[e]], 1);
}

// slab alloc (wave scan + one atomic/wave) + dinv fused
__global__ void k_alloc(const int* __restrict__ deg, int* __restrict__ counter,
                        int* __restrict__ rowstart, float* __restrict__ dinv) {
    int i = blockIdx.x * blockDim.x + threadIdx.x;
    int lane = threadIdx.x & 63;
    int d = (i < NN) ? deg[i] : 0;
    int v = d;
    #pragma unroll
    for (int off = 1; off < 64; off <<= 1) {
        int t = __shfl_up(v, off, 64);
        if (lane >= off) v += t;
    }
    int total = __shfl(v, 63, 64);
    int base = 0;
    if (lane == 63) base = atomicAdd(counter, total);
    base = __shfl(base, 63, 64);
    if (i < NN) {
        rowstart[i] = base + v - d;
        dinv[i] = 1.0f / sqrtf((float)(d == 0 ? 1 : d));
    }
}

// fused edge record: low32 = col, high32 = fp32 weight bits
__global__ void k_fill(const int* __restrict__ row, const int* __restrict__ col,
                       const float* __restrict__ ea, const float* __restrict__ dinv,
                       const int* __restrict__ rowstart, int* __restrict__ fill,
                       ull* __restrict__ ecv) {
    int e = blockIdx.x * blockDim.x + threadIdx.x;
    if (e < NE) {
        int r = row[e], c = col[e];
        int pos = rowstart[r] + atomicAdd(&fill[r], 1);
        float v = dinv[r] * ea[e] * dinv[c];
        ull rec = (ull)(unsigned int)c | ((ull)__float_as_uint(v) << 32);
        ecv[pos] = rec;
    }
}

// fp32 -> bf16 cast (x staging for the first spmm's gather)
__global__ void k_cast(const float* __restrict__ x, unsigned short* __restrict__ xb) {
    int i = blockIdx.x * blockDim.x + threadIdx.x;
    if (i < NN * DF) xb[i] = f2bf(x[i]);
}

// ---------------- polynomial coefficients ----------------
// xs_k,m = sum_j c[k][j] S^j x  (S = normalized adjacency, m-independent).
// gamma[k][j] = sum_m w_m c_{k,m,j}. Computed by one thread (trivial work).
__global__ void k_coef(const float* __restrict__ alphas, const float* __restrict__ w,
                       const float* __restrict__ a_arr, const float* __restrict__ b_arr,
                       float* __restrict__ gamma) {
    if (blockIdx.x != 0 || threadIdx.x != 0) return;
    float g[OUT_K][OUT_K];
    for (int k = 0; k < OUT_K; ++k)
        for (int j = 0; j < OUT_K; ++j) g[k][j] = 0.f;
    for (int m = 0; m < MM; ++m) {
        float a = a_arr[m], b = b_arr[m], wm = w[m];
        float c[OUT_K][OUT_K];
        for (int k = 0; k < OUT_K; ++k)
            for (int j = 0; j < OUT_K; ++j) c[k][j] = 0.f;
        c[0][0] = 1.f;
        float al0 = alphas[m];
        c[1][0] = al0 * 0.5f * (a - b);           // l=-1,r=1: coef1=(a-b)/2
        c[1][1] = al0 * 0.5f * (a + b + 2.f);     // coef2=(a+b+2)/2
        for (int L = 2; L <= 3; ++L) {
            float Lf = (float)L;
            float alL = alphas[(L - 1) * MM + m];
            float alm = alphas[(L - 2) * MM + m];
            float ab = a + b;
            float t2L = 2.f * Lf + ab;
            float coef_l = 2.f * Lf * (Lf + ab) * (t2L - 2.f);
            float inv = 1.f / coef_l;
            float t1 = alL * ((t2L - 1.f) * t2L * (t2L - 2.f)) * inv;
            float t2 = alL * ((t2L - 1.f) * (a * a - b * b)) * inv;
            float t3 = alL * alm * (2.f * (Lf - 1.f + a) * (Lf - 1.f + b) * t2L) * inv;
            for (int j = 0; j < OUT_K; ++j) {
                float prev_shift = (j > 0) ? c[L - 1][j - 1] : 0.f;
                c[L][j] = t1 * prev_shift - t2 * c[L - 1][j] - t3 * c[L - 2][j];
            }
        }
        for (int k = 0; k < OUT_K; ++k)
            for (int j = 0; j < OUT_K; ++j) g[k][j] += wm * c[k][j];
    }
    for (int k = 0; k < OUT_K; ++k)
        for (int j = 0; j < OUT_K; ++j) gamma[k * OUT_K + j] = g[k][j];
}

// ---------------- SpMM: y = S xin (bf16 gather, fp32 out + bf16 copy) ----------------
// Wave per row, lane = feature. CH-batched gathers for memory-level parallelism.
__global__ __launch_bounds__(256) void k_spmm(
    const int* __restrict__ rowstart, const int* __restrict__ deg,
    const ull* __restrict__ ecv, const unsigned short* __restrict__ xin,
    float* __restrict__ yout, unsigned short* __restrict__ bout) {
    int r = (blockIdx.x * blockDim.x + threadIdx.x) >> 6;
    int lane = threadIdx.x & 63;
    if (r >= NN) return;
    int s = rowstart[r], e = s + deg[r];
    float acc = 0.f;
    const int CH = 8;
    int i = s;
    for (; i + CH <= e; i += CH) {
        ull ec[CH];
        #pragma unroll
        for (int j = 0; j < CH; ++j) ec[j] = __builtin_nontemporal_load(&ecv[i + j]);
        unsigned short gth[CH];
        float vv[CH];
        #pragma unroll
        for (int j = 0; j < CH; ++j) {
            int c = (int)(unsigned int)(ec[j] & 0xFFFFFFFFull);
            vv[j] = __uint_as_float((unsigned int)(ec[j] >> 32));
            gth[j] = xin[c * DF + lane];
        }
        #pragma unroll
        for (int j = 0; j < CH; ++j) acc += vv[j] * bf2f(gth[j]);
    }
    for (; i < e; ++i) {
        ull ec = __builtin_nontemporal_load(&ecv[i]);
        int c = (int)(unsigned int)(ec & 0xFFFFFFFFull);
        float v = __uint_as_float((unsigned int)(ec >> 32));
        acc += v * bf2f(xin[c * DF + lane]);
    }
    yout[r * DF + lane] = acc;
    bout[r * DF + lane] = f2bf(acc);
}

// ---------------- final combine: out[r,k,:] = sum_j gamma[k][j] * y_j[r,:] ----------------
__global__ __launch_bounds__(256) void k_combine(
    const float* __restrict__ x, const float* __restrict__ y1,
    const float* __restrict__ y2, const float* __restrict__ y3,
    const float* __restrict__ gamma, float* __restrict__ out) {
    int i = blockIdx.x * blockDim.x + threadIdx.x;
    if (i >= NN * DF) return;
    int r = i >> 6, d = i & 63;
    float v0 = x[i], v1 = y1[i], v2 = y2[i], v3 = y3[i];
    #pragma unroll
    for (int k = 0; k < OUT_K; ++k) {
        float o = gamma[k * OUT_K + 0] * v0 + gamma[k * OUT_K + 1] * v1 +
                  gamma[k * OUT_K + 2] * v2 + gamma[k * OUT_K + 3] * v3;
        out[(r * OUT_K + k) * DF + d] = o;
    }
}

// ---------------- launch ----------------

extern "C" void kernel_launch(void* const* d_in, const int* in_sizes, int n_in,
                              void* d_out, int out_size, void* d_ws, size_t ws_size,
                              hipStream_t stream) {
    const float* x      = (const float*)d_in[0];
    const int*   ei     = (const int*)d_in[1];
    const float* ea     = (const float*)d_in[2];
    const float* alphas = (const float*)d_in[3];
    const float* w      = (const float*)d_in[4];
    const float* a_arr  = (const float*)d_in[5];
    const float* b_arr  = (const float*)d_in[6];
    float* out = (float*)d_out;
    const int* row = ei;
    const int* col = ei + NE;

    char* ws = (char*)d_ws;
    size_t off = 0;
    auto alloc = [&](size_t bytes) {
        void* p = ws + off;
        off = (off + bytes + 255) & ~(size_t)255;
        return p;
    };
    int* deg      = (int*)alloc((size_t)(2 * NN + 1) * sizeof(int));
    int* fill     = deg + NN;
    int* counter  = deg + 2 * NN;
    int* rowstart = (int*)alloc((size_t)NN * sizeof(int));
    float* dinv   = (float*)alloc((size_t)NN * sizeof(float));
    ull* ecv      = (ull*)alloc((size_t)NE * sizeof(ull));
    unsigned short* xb0 = (unsigned short*)alloc((size_t)NN * DF * sizeof(unsigned short));
    unsigned short* xb1 = (unsigned short*)alloc((size_t)NN * DF * sizeof(unsigned short));
    unsigned short* xb2 = (unsigned short*)alloc((size_t)NN * DF * sizeof(unsigned short));
    float* y1 = (float*)alloc((size_t)NN * DF * sizeof(float));
    float* y2 = (float*)alloc((size_t)NN * DF * sizeof(float));
    float* y3 = (float*)alloc((size_t)NN * DF * sizeof(float));
    float* gamma = (float*)alloc((size_t)OUT_K * OUT_K * sizeof(float));

    (void)hipMemsetAsync(deg, 0, (size_t)(2 * NN + 1) * sizeof(int), stream);

    k_deg<<<(NE + 255) / 256, 256, 0, stream>>>(row, deg);
    k_alloc<<<(NN + 255) / 256, 256, 0, stream>>>(deg, counter, rowstart, dinv);
    k_fill<<<(NE + 255) / 256, 256, 0, stream>>>(row, col, ea, dinv, rowstart, fill, ecv);
    k_cast<<<(NN * DF + 255) / 256, 256, 0, stream>>>(x, xb0);
    k_coef<<<1, 64, 0, stream>>>(alphas, w, a_arr, b_arr, gamma);

    int blocks = (NN + 3) / 4;  // wave per row, 4 rows per 256-thread block
    k_spmm<<<blocks, 256, 0, stream>>>(rowstart, deg, ecv, xb0, y1, xb1);
    k_spmm<<<blocks, 256, 0, stream>>>(rowstart, deg, ecv, xb1, y2, xb2);
    k_spmm<<<blocks, 256, 0, stream>>>(rowstart, deg, ecv, xb2, y3, xb0);

    k_combine<<<(NN * DF + 255) / 256, 256, 0, stream>>>(x, y1, y2, y3, gamma, out);
}

// Round 8
// 273.656 us; speedup vs baseline: 3.5454x; 1.2545x over previous
//
#include <hip/hip_runtime.h>
#include <hip/hip_fp16.h>

#define NN 50000      // nodes (fits in 16 bits: col packed as ushort)
#define NE 800000     // edges
#define DF 64         // features
#define MM 11         // (a,b) tuples
#define OUT_K 4       // DEPTH+1 output planes
#define PAD 16        // row slabs padded to multiple of PAD; CH = PAD
#define SLAB_CAP (NE + (PAD - 1) * NN + 64)

__device__ __forceinline__ float bf2f(unsigned short u) {
    union { unsigned int i; float f; } v; v.i = ((unsigned int)u) << 16; return v.f;
}
__device__ __forceinline__ unsigned short f2bf(float f) {
    union { float f; unsigned int i; } v; v.f = f;
    unsigned int u = v.i + 0x7FFFu + ((v.i >> 16) & 1u);
    return (unsigned short)(u >> 16);
}

// ---------------- CSR build ----------------

__global__ void k_deg(const int* __restrict__ row, int* __restrict__ deg) {
    int e = blockIdx.x * blockDim.x + threadIdx.x;
    if (e < NE) atomicAdd(&deg[row[e]], 1);
}

// slab alloc (padded to PAD, wave scan + one atomic/wave) + dinv + gamma (thread 0)
__global__ void k_alloc(const int* __restrict__ deg, int* __restrict__ counter,
                        int* __restrict__ rowstart, float* __restrict__ dinv,
                        const float* __restrict__ alphas, const float* __restrict__ w,
                        const float* __restrict__ a_arr, const float* __restrict__ b_arr,
                        float* __restrict__ gamma) {
    int i = blockIdx.x * blockDim.x + threadIdx.x;
    int lane = threadIdx.x & 63;
    int d = (i < NN) ? deg[i] : 0;
    int dp = (d + PAD - 1) & ~(PAD - 1);
    int v = dp;
    #pragma unroll
    for (int off = 1; off < 64; off <<= 1) {
        int t = __shfl_up(v, off, 64);
        if (lane >= off) v += t;
    }
    int total = __shfl(v, 63, 64);
    int base = 0;
    if (lane == 63) base = atomicAdd(counter, total);
    base = __shfl(base, 63, 64);
    if (i < NN) {
        rowstart[i] = base + v - dp;
        dinv[i] = 1.0f / sqrtf((float)(d == 0 ? 1 : d));
    }
    // gamma[k][j] = sum_m w_m c_{k,m,j} where xs_k,m = sum_j c[k][j] S^j x
    if (i == 0) {
        float g[OUT_K][OUT_K];
        for (int k = 0; k < OUT_K; ++k)
            for (int j = 0; j < OUT_K; ++j) g[k][j] = 0.f;
        for (int m = 0; m < MM; ++m) {
            float a = a_arr[m], b = b_arr[m], wm = w[m];
            float c[OUT_K][OUT_K];
            for (int k = 0; k < OUT_K; ++k)
                for (int j = 0; j < OUT_K; ++j) c[k][j] = 0.f;
            c[0][0] = 1.f;
            float al0 = alphas[m];
            c[1][0] = al0 * 0.5f * (a - b);        // l=-1,r=1
            c[1][1] = al0 * 0.5f * (a + b + 2.f);
            for (int L = 2; L <= 3; ++L) {
                float Lf = (float)L;
                float alL = alphas[(L - 1) * MM + m];
                float alm = alphas[(L - 2) * MM + m];
                float ab = a + b;
                float t2L = 2.f * Lf + ab;
                float coef_l = 2.f * Lf * (Lf + ab) * (t2L - 2.f);
                float inv = 1.f / coef_l;
                float t1 = alL * ((t2L - 1.f) * t2L * (t2L - 2.f)) * inv;
                float t2 = alL * ((t2L - 1.f) * (a * a - b * b)) * inv;
                float t3 = alL * alm * (2.f * (Lf - 1.f + a) * (Lf - 1.f + b) * t2L) * inv;
                for (int j = 0; j < OUT_K; ++j) {
                    float ps = (j > 0) ? c[L - 1][j - 1] : 0.f;
                    c[L][j] = t1 * ps - t2 * c[L - 1][j] - t3 * c[L - 2][j];
                }
            }
            for (int k = 0; k < OUT_K; ++k)
                for (int j = 0; j < OUT_K; ++j) g[k][j] += wm * c[k][j];
        }
        for (int k = 0; k < OUT_K; ++k)
            for (int j = 0; j < OUT_K; ++j) gamma[k * OUT_K + j] = g[k][j];
    }
}

// fill (4-byte records: low16 = col, high16 = fp16 weight) + bf16 cast of x fused
__global__ void k_fill_cast(const int* __restrict__ row, const int* __restrict__ col,
                            const float* __restrict__ ea, const float* __restrict__ dinv,
                            const int* __restrict__ rowstart, int* __restrict__ fill,
                            unsigned int* __restrict__ ecv,
                            const float* __restrict__ x, unsigned short* __restrict__ xb) {
    int t = blockIdx.x * blockDim.x + threadIdx.x;
    if (t < NE) {
        int r = row[t], c = col[t];
        int pos = rowstart[r] + atomicAdd(&fill[r], 1);
        float v = dinv[r] * ea[t] * dinv[c];
        unsigned short hb = __half_as_ushort(__float2half(v));
        ecv[pos] = (unsigned int)(unsigned short)c | ((unsigned int)hb << 16);
    } else {
        int j = t - NE;
        if (j < NN * DF) xb[j] = f2bf(x[j]);
    }
}

// ---------------- SpMM: wave per row, lane = feature, PAD-wide batches, no tail ----
__device__ __forceinline__ float spmm_row(const unsigned int* __restrict__ ecv,
                                          int s, int n,
                                          const unsigned short* __restrict__ xin,
                                          int lane) {
    float acc = 0.f;
    for (int i = s; i < s + n; i += PAD) {
        unsigned int rec[PAD];
        #pragma unroll
        for (int j = 0; j < PAD; ++j) rec[j] = __builtin_nontemporal_load(&ecv[i + j]);
        unsigned short g[PAD];
        float vv[PAD];
        #pragma unroll
        for (int j = 0; j < PAD; ++j) {
            int c = (int)(rec[j] & 0xFFFFu);
            vv[j] = __half2float(__ushort_as_half((unsigned short)(rec[j] >> 16)));
            g[j] = xin[c * DF + lane];
        }
        #pragma unroll
        for (int j = 0; j < PAD; ++j) acc += vv[j] * bf2f(g[j]);
    }
    return acc;
}

__global__ __launch_bounds__(256) void k_spmm(
    const int* __restrict__ rowstart, const int* __restrict__ deg,
    const unsigned int* __restrict__ ecv, const unsigned short* __restrict__ xin,
    float* __restrict__ yout, unsigned short* __restrict__ bout) {
    int r = (blockIdx.x * blockDim.x + threadIdx.x) >> 6;
    int lane = threadIdx.x & 63;
    if (r >= NN) return;
    int s = rowstart[r];
    int n = (deg[r] + PAD - 1) & ~(PAD - 1);
    float acc = spmm_row(ecv, s, n, xin, lane);
    yout[r * DF + lane] = acc;
    bout[r * DF + lane] = f2bf(acc);
}

// third SpMM with the output combine fused (y3 never hits memory)
__global__ __launch_bounds__(256) void k_spmm_comb(
    const int* __restrict__ rowstart, const int* __restrict__ deg,
    const unsigned int* __restrict__ ecv, const unsigned short* __restrict__ xin,
    const float* __restrict__ x, const float* __restrict__ y1,
    const float* __restrict__ y2, const float* __restrict__ gamma,
    float* __restrict__ out) {
    int r = (blockIdx.x * blockDim.x + threadIdx.x) >> 6;
    int lane = threadIdx.x & 63;
    if (r >= NN) return;
    int s = rowstart[r];
    int n = (deg[r] + PAD - 1) & ~(PAD - 1);
    float v3 = spmm_row(ecv, s, n, xin, lane);
    int i = r * DF + lane;
    float v0 = x[i], v1 = y1[i], v2 = y2[i];
    float gm[OUT_K * OUT_K];
    #pragma unroll
    for (int t = 0; t < OUT_K * OUT_K; ++t) gm[t] = gamma[t];
    #pragma unroll
    for (int k = 0; k < OUT_K; ++k) {
        float o = gm[k * OUT_K + 0] * v0 + gm[k * OUT_K + 1] * v1 +
                  gm[k * OUT_K + 2] * v2 + gm[k * OUT_K + 3] * v3;
        out[(r * OUT_K + k) * DF + lane] = o;
    }
}

// ---------------- launch ----------------

extern "C" void kernel_launch(void* const* d_in, const int* in_sizes, int n_in,
                              void* d_out, int out_size, void* d_ws, size_t ws_size,
                              hipStream_t stream) {
    const float* x      = (const float*)d_in[0];
    const int*   ei     = (const int*)d_in[1];
    const float* ea     = (const float*)d_in[2];
    const float* alphas = (const float*)d_in[3];
    const float* w      = (const float*)d_in[4];
    const float* a_arr  = (const float*)d_in[5];
    const float* b_arr  = (const float*)d_in[6];
    float* out = (float*)d_out;
    const int* row = ei;
    const int* col = ei + NE;

    char* ws = (char*)d_ws;
    size_t off = 0;
    auto alloc = [&](size_t bytes) {
        void* p = ws + off;
        off = (off + bytes + 255) & ~(size_t)255;
        return p;
    };
    // deg/fill/counter then ecv are contiguous so ONE memset zeroes all
    // (ecv pad slots must be 0: col=0, fp16 val=0).
    int* deg      = (int*)alloc((size_t)(2 * NN + 1) * sizeof(int));
    int* fill     = deg + NN;
    int* counter  = deg + 2 * NN;
    unsigned int* ecv = (unsigned int*)alloc((size_t)SLAB_CAP * sizeof(unsigned int));
    size_t zero_end = off;
    int* rowstart = (int*)alloc((size_t)NN * sizeof(int));
    float* dinv   = (float*)alloc((size_t)NN * sizeof(float));
    unsigned short* xb0 = (unsigned short*)alloc((size_t)NN * DF * sizeof(unsigned short));
    unsigned short* xb1 = (unsigned short*)alloc((size_t)NN * DF * sizeof(unsigned short));
    unsigned short* xb2 = (unsigned short*)alloc((size_t)NN * DF * sizeof(unsigned short));
    float* y1 = (float*)alloc((size_t)NN * DF * sizeof(float));
    float* y2 = (float*)alloc((size_t)NN * DF * sizeof(float));
    float* gamma = (float*)alloc((size_t)OUT_K * OUT_K * sizeof(float));

    (void)hipMemsetAsync(deg, 0, zero_end, stream);

    k_deg<<<(NE + 255) / 256, 256, 0, stream>>>(row, deg);
    k_alloc<<<(NN + 255) / 256, 256, 0, stream>>>(deg, counter, rowstart, dinv,
                                                  alphas, w, a_arr, b_arr, gamma);
    k_fill_cast<<<(NE + NN * DF + 255) / 256, 256, 0, stream>>>(
        row, col, ea, dinv, rowstart, fill, ecv, x, xb0);

    int blocks = (NN + 3) / 4;  // wave per row, 4 rows per 256-thread block
    k_spmm<<<blocks, 256, 0, stream>>>(rowstart, deg, ecv, xb0, y1, xb1);
    k_spmm<<<blocks, 256, 0, stream>>>(rowstart, deg, ecv, xb1, y2, xb2);
    k_spmm_comb<<<blocks, 256, 0, stream>>>(rowstart, deg, ecv, xb2, x, y1, y2,
                                            gamma, out);
}